// Round 7
// baseline (231.312 us; speedup 1.0000x reference)
//
#include <hip/hip_runtime.h>
#include <math.h>

#define NROWS 16384
#define DIM   16
#define KC    512                 // rows per LDS chunk
#define NCH   (NROWS / KC)        // 32 chunks
#define WGT   512                 // 8 waves
#define RPW   4                   // rows per wave
#define RPWG  32                  // rows per workgroup
#define NT4   (NROWS / 4)         // 4096 float4 slots per plane

typedef float vfloat4 __attribute__((ext_vector_type(4)));   // native vec for builtins

static __device__ __forceinline__ void fma4(float4& a, float s, const float4& b) {
    a.x = fmaf(s, b.x, a.x);
    a.y = fmaf(s, b.y, a.y);
    a.z = fmaf(s, b.z, a.z);
    a.w = fmaf(s, b.w, a.w);
}
static __device__ __forceinline__ float dot4(const float4& a) {
    return a.x * a.x + a.y * a.y + a.z * a.z + a.w * a.w;
}
static __device__ __forceinline__ float4 scale4(const float4& a, float s) {
    return make_float4(a.x * s, a.y * s, a.z * s, a.w * s);
}

// ---------------- Kernel 1: xt = logmap0(x), stored plane-major ----------------
// xtp[(j*4+s)*NT4 + t] = quad j of tangent row (4t+s). This makes kernel-2
// staging loads lane-contiguous 16B (perfect coalescing).
__global__ void hyp_logmap0(const float* __restrict__ x, float4* __restrict__ xtp) {
    int tid = blockIdx.x * blockDim.x + threadIdx.x;   // 16384 threads
    int s = tid >> 12;          // 0..3
    int t = tid & (NT4 - 1);    // 0..4095
    int row = 4 * t + s;
    const float4* src = (const float4*)(x + (size_t)row * DIM);
    float4 q0 = src[0], q1 = src[1], q2 = src[2], q3 = src[3];
    float n2 = dot4(q0) + dot4(q1) + dot4(q2) + dot4(q3);
    float n  = fmaxf(sqrtf(n2), 1e-15f);
    float arg = fminf(n, 1.0f - 1e-7f);
    float f = atanhf(arg) / n;
    xtp[(0 * 4 + s) * NT4 + t] = scale4(q0, f);   // consecutive tid -> contiguous
    xtp[(1 * 4 + s) * NT4 + t] = scale4(q1, f);
    xtp[(2 * 4 + s) * NT4 + t] = scale4(q2, f);
    xtp[(3 * 4 + s) * NT4 + t] = scale4(q3, f);
}

// ---------------- Kernel 2: out = proj(expmap0(adj @ xt)) ----------------
__global__ __launch_bounds__(WGT, 4) void hyp_agg(
        const float* __restrict__ adj, const float4* __restrict__ xtp,
        float* __restrict__ out) {
    // Double-buffered xt chunk: planes[buf][j*4+s][t], row kk = 4t+s of chunk.
    // Reads at fixed s are lane-contiguous float4 -> conflict-free ds_read_b128.
    __shared__ float4 planes[2][16][KC / 4];   // 2 * 16 * 128 * 16B = 64 KB

    const int tid  = threadIdx.x;
    const int lane = tid & 63;
    const int wave = tid >> 6;
    const int rowBase = blockIdx.x * RPWG + wave * RPW;

    const float* a0 = adj + (size_t)(rowBase + 0) * NROWS;
    const float* a1 = adj + (size_t)(rowBase + 1) * NROWS;
    const float* a2 = adj + (size_t)(rowBase + 2) * NROWS;
    const float* a3 = adj + (size_t)(rowBase + 3) * NROWS;

    float4 acc[RPW][4];
#pragma unroll
    for (int r = 0; r < RPW; ++r)
#pragma unroll
        for (int j = 0; j < 4; ++j)
            acc[r][j] = make_float4(0.f, 0.f, 0.f, 0.f);

    // Async stage chunk starting at row kc into buffer `buf`.
    // Each wave issues 4 global_load_lds (16B/lane): covers 16 planes x 2 halves.
    auto stage = [&](int buf, int kc) {
#pragma unroll
        for (int i = 0; i < 4; ++i) {
            const int idx = wave * 4 + i;   // 0..31
            const int p   = idx >> 1;       // plane 0..15
            const int h   = idx & 1;        // half 0..1
            const float4* src = xtp + (size_t)p * NT4 + (kc >> 2) + h * 64 + lane;
            __builtin_amdgcn_global_load_lds(
                (const __attribute__((address_space(1))) void*)src,
                (__attribute__((address_space(3))) void*)&planes[buf][p][h * 64],
                16, 0, 0);
        }
    };

    stage(0, 0);
    __syncthreads();

    for (int c = 0; c < NCH; ++c) {
        const int kc  = c * KC;
        const int buf = c & 1;
        if (c + 1 < NCH) stage(buf ^ 1, kc + KC);   // async prefetch next chunk

#pragma unroll
        for (int it = 0; it < KC / 256; ++it) {
            const int col = kc + it * 256 + 4 * lane;
            // adj: streaming, zero reuse -> nontemporal 16B/lane (1KB/wave/instr)
            vfloat4 v0 = __builtin_nontemporal_load((const vfloat4*)(a0 + col));
            vfloat4 v1 = __builtin_nontemporal_load((const vfloat4*)(a1 + col));
            vfloat4 v2 = __builtin_nontemporal_load((const vfloat4*)(a2 + col));
            vfloat4 v3 = __builtin_nontemporal_load((const vfloat4*)(a3 + col));
#pragma unroll
            for (int s = 0; s < 4; ++s) {
                const int t = it * 64 + lane;
                float4 q0 = planes[buf][0 * 4 + s][t];
                float4 q1 = planes[buf][1 * 4 + s][t];
                float4 q2 = planes[buf][2 * 4 + s][t];
                float4 q3 = planes[buf][3 * 4 + s][t];
                float c0 = v0[s];
                float c1 = v1[s];
                float c2 = v2[s];
                float c3 = v3[s];
                fma4(acc[0][0], c0, q0); fma4(acc[0][1], c0, q1);
                fma4(acc[0][2], c0, q2); fma4(acc[0][3], c0, q3);
                fma4(acc[1][0], c1, q0); fma4(acc[1][1], c1, q1);
                fma4(acc[1][2], c1, q2); fma4(acc[1][3], c1, q3);
                fma4(acc[2][0], c2, q0); fma4(acc[2][1], c2, q1);
                fma4(acc[2][2], c2, q2); fma4(acc[2][3], c2, q3);
                fma4(acc[3][0], c3, q0); fma4(acc[3][1], c3, q1);
                fma4(acc[3][2], c3, q2); fma4(acc[3][3], c3, q3);
            }
        }
        // drains staging loads (vmcnt(0)) + makes buf^1 safe to overwrite next iter
        __syncthreads();
    }

    // cross-lane butterfly reduce (lanes split K)
#pragma unroll
    for (int r = 0; r < RPW; ++r) {
#pragma unroll
        for (int j = 0; j < 4; ++j) {
            float4 v = acc[r][j];
#pragma unroll
            for (int m = 1; m < 64; m <<= 1) {
                v.x += __shfl_xor(v.x, m, 64);
                v.y += __shfl_xor(v.y, m, 64);
                v.z += __shfl_xor(v.z, m, 64);
                v.w += __shfl_xor(v.w, m, 64);
            }
            acc[r][j] = v;
        }
    }

    // epilogue: expmap0 + proj; all lanes compute (uniform), lane 0 stores
#pragma unroll
    for (int r = 0; r < RPW; ++r) {
        float4 s0 = acc[r][0], s1 = acc[r][1], s2 = acc[r][2], s3 = acc[r][3];
        float n2 = dot4(s0) + dot4(s1) + dot4(s2) + dot4(s3);
        float n  = fmaxf(sqrtf(n2), 1e-15f);
        float t  = tanhf(n);
        float fac = t / n;                         // expmap0 factor
        float ny  = fmaxf(t, 1e-15f);              // ||y|| = tanh(n)
        const float MAX_NORM = 1.0f - 1e-5f;
        float sc  = (ny > MAX_NORM) ? (MAX_NORM / ny) : 1.0f;
        float tot = fac * sc;
        if (lane == 0) {
            float4* dst = (float4*)(out + (size_t)(rowBase + r) * DIM);
            dst[0] = scale4(s0, tot);
            dst[1] = scale4(s1, tot);
            dst[2] = scale4(s2, tot);
            dst[3] = scale4(s3, tot);
        }
    }
}

extern "C" void kernel_launch(void* const* d_in, const int* in_sizes, int n_in,
                              void* d_out, int out_size, void* d_ws, size_t ws_size,
                              hipStream_t stream) {
    const float* x   = (const float*)d_in[0];   // [16384, 16]
    const float* adj = (const float*)d_in[1];   // [16384, 16384]
    float* out  = (float*)d_out;                // [16384, 16]
    float4* xtp = (float4*)d_ws;                // plane-major tangent, 1 MiB

    hipLaunchKernelGGL(hyp_logmap0, dim3(NROWS / 256), dim3(256), 0, stream, x, xtp);
    hipLaunchKernelGGL(hyp_agg, dim3(NROWS / RPWG), dim3(WGT), 0, stream, adj, xtp, out);
}